// Round 1
// baseline (411.745 us; speedup 1.0000x reference)
//
#include <hip/hip_runtime.h>

// Problem constants
#define D_    2048
#define OUT_  2048
#define E_    8
#define R_    16
#define KX    2176          // D_ + E_*R_  (K-extended GEMM depth)
#define M_    16384         // B*S tokens
#define SCALING_F 2.0f      // ALPHA / R = 32/16

typedef unsigned short ushort_t;
typedef unsigned short ushort8 __attribute__((ext_vector_type(8)));
typedef __bf16 bf16x8 __attribute__((ext_vector_type(8)));
typedef float f32x4 __attribute__((ext_vector_type(4)));

__device__ __forceinline__ ushort_t f2bf(float f) {
  unsigned u = __float_as_uint(f);
  u += 0x7FFFu + ((u >> 16) & 1u);   // round-to-nearest-even
  return (ushort_t)(u >> 16);
}

#define GLOAD16(gp, lp)                                                        \
  __builtin_amdgcn_global_load_lds(                                            \
      (const __attribute__((address_space(1))) void*)(gp),                     \
      (__attribute__((address_space(3))) void*)(lp), 16, 0, 0)

// ---------------- W_ext prep: [OUT_][KX] bf16 = bf16(W_base) | Bw[e][o][r] ---
__global__ __launch_bounds__(256) void wprep_kernel(
    const float* __restrict__ W, const float* __restrict__ Bw,
    ushort_t* __restrict__ wext)
{
  const int o = blockIdx.x;     // output row
  const int t = threadIdx.x;    // 0..255
  const float* wr = W + (size_t)o * D_ + t * 8;
  float4 v0 = *(const float4*)wr;
  float4 v1 = *(const float4*)(wr + 4);
  ushort8 wb;
  wb[0] = f2bf(v0.x); wb[1] = f2bf(v0.y); wb[2] = f2bf(v0.z); wb[3] = f2bf(v0.w);
  wb[4] = f2bf(v1.x); wb[5] = f2bf(v1.y); wb[6] = f2bf(v1.z); wb[7] = f2bf(v1.w);
  *(ushort8*)(wext + (size_t)o * KX + t * 8) = wb;
  if (t < E_ * R_) {
    const int e = t >> 4, r = t & 15;
    wext[(size_t)o * KX + D_ + t] = f2bf(Bw[((size_t)e * OUT_ + o) * R_ + r]);
  }
}

// ---------------- x_ext prep: router(fp64) + argmax + h = x·A[e]^T ----------
__global__ __launch_bounds__(256) void xprep_kernel(
    const float* __restrict__ x, const float* __restrict__ rW,
    const float* __restrict__ A, ushort_t* __restrict__ xext)
{
  __shared__ double lred[4][E_];
  __shared__ float  hred[4][R_];
  __shared__ float  hsh[R_];
  __shared__ int    esel;

  const int m = blockIdx.x;     // token
  const int t = threadIdx.x;    // 0..255
  const int lane = t & 63, wid = t >> 6;

  const float* xr = x + (size_t)m * D_ + t * 8;
  float4 v0 = *(const float4*)xr;
  float4 v1 = *(const float4*)(xr + 4);
  float xv[8] = {v0.x, v0.y, v0.z, v0.w, v1.x, v1.y, v1.z, v1.w};

  // write bf16 x slice
  ushort8 xb;
  #pragma unroll
  for (int j = 0; j < 8; ++j) xb[j] = f2bf(xv[j]);
  *(ushort8*)(xext + (size_t)m * KX + t * 8) = xb;

  // router logits, fp64 accumulation (argmax determinism)
  double le[E_];
  #pragma unroll
  for (int e = 0; e < E_; ++e) {
    const float* w = rW + (size_t)e * D_ + t * 8;
    float4 w0 = *(const float4*)w;
    float4 w1 = *(const float4*)(w + 4);
    double s = (double)xv[0] * w0.x + (double)xv[1] * w0.y
             + (double)xv[2] * w0.z + (double)xv[3] * w0.w
             + (double)xv[4] * w1.x + (double)xv[5] * w1.y
             + (double)xv[6] * w1.z + (double)xv[7] * w1.w;
    le[e] = s;
  }
  #pragma unroll
  for (int e = 0; e < E_; ++e)
    #pragma unroll
    for (int off = 32; off; off >>= 1)
      le[e] += __shfl_xor(le[e], off, 64);
  if (lane == 0) {
    #pragma unroll
    for (int e = 0; e < E_; ++e) lred[wid][e] = le[e];
  }
  __syncthreads();
  if (t == 0) {
    double best = -1e300; int bi = 0;
    #pragma unroll
    for (int e = 0; e < E_; ++e) {
      double s = lred[0][e] + lred[1][e] + lred[2][e] + lred[3][e];
      if (s > best) { best = s; bi = e; }   // first-max tie-break (jnp.argmax)
    }
    esel = bi;
  }
  __syncthreads();
  const int e = esel;

  // h[r] = x · A[e][r][:]
  float h[R_];
  const float* Ae = A + (size_t)e * R_ * D_ + t * 8;
  #pragma unroll
  for (int r = 0; r < R_; ++r) {
    const float* ar = Ae + (size_t)r * D_;
    float4 a0 = *(const float4*)ar;
    float4 a1 = *(const float4*)(ar + 4);
    h[r] = xv[0] * a0.x + xv[1] * a0.y + xv[2] * a0.z + xv[3] * a0.w
         + xv[4] * a1.x + xv[5] * a1.y + xv[6] * a1.z + xv[7] * a1.w;
  }
  #pragma unroll
  for (int r = 0; r < R_; ++r)
    #pragma unroll
    for (int off = 32; off; off >>= 1)
      h[r] += __shfl_xor(h[r], off, 64);
  if (lane == 0) {
    #pragma unroll
    for (int r = 0; r < R_; ++r) hred[wid][r] = h[r];
  }
  __syncthreads();
  if (t < R_) hsh[t] = (hred[0][t] + hred[1][t] + hred[2][t] + hred[3][t]) * SCALING_F;
  __syncthreads();

  if (t < E_ * R_) {
    float val = ((t >> 4) == e) ? hsh[t & 15] : 0.0f;
    xext[(size_t)m * KX + D_ + t] = f2bf(val);
  }
}

// ---------------- GEMM: C[M_][OUT_] = Xext @ Wext^T + bias -----------------
// m97 structure: 128x128 tile, BK=64, 4 waves (2x2), global_load_lds width=16
#define BM 128
#define BN 128
#define BK 64
#define NT (OUT_ / BN)   // 16 tiles in N

__global__ __launch_bounds__(256) void gemm_kernel(
    const ushort_t* __restrict__ Ag,   // [M_][KX] bf16
    const ushort_t* __restrict__ Bg,   // [OUT_][KX] bf16
    const float* __restrict__ bias,
    float* __restrict__ C)
{
  __shared__ __attribute__((aligned(16))) ushort_t As[BM * BK];
  __shared__ __attribute__((aligned(16))) ushort_t Bs[BN * BK];

  const int bid = blockIdx.x;
  const int bn = bid & (NT - 1);
  const int bm = bid >> 4;
  const int t = threadIdx.x;
  const int lane = t & 63, w = t >> 6;
  const int wm = w >> 1, wn = w & 1;        // 2x2 wave grid, 64x64 each
  const int lr = lane & 15, lg = lane >> 4; // fragment row / k-group

  f32x4 acc[4][4] = {};

  const size_t aBase = (size_t)(bm * BM) * KX;
  const size_t bBase = (size_t)(bn * BN) * KX;

  for (int k0 = 0; k0 < KX; k0 += BK) {
    // stage 128x64 bf16 A and B tiles: 4 x 256 lanes x 16B each
    #pragma unroll
    for (int j = 0; j < 4; ++j) {
      const int idx = j * 256 + t;
      const int row = idx >> 3;          // 8 chunks of 8 bf16 per 64-wide row
      const int col = (idx & 7) * 8;
      GLOAD16(Ag + aBase + (size_t)row * KX + k0 + col, (ushort_t*)As + (size_t)idx * 8);
      GLOAD16(Bg + bBase + (size_t)row * KX + k0 + col, (ushort_t*)Bs + (size_t)idx * 8);
    }
    __syncthreads();

    #pragma unroll
    for (int kk = 0; kk < 2; ++kk) {
      bf16x8 af[4], bfr[4];
      #pragma unroll
      for (int i = 0; i < 4; ++i)
        af[i] = *(const bf16x8*)&As[(wm * 64 + i * 16 + lr) * BK + kk * 32 + lg * 8];
      #pragma unroll
      for (int i = 0; i < 4; ++i)
        bfr[i] = *(const bf16x8*)&Bs[(wn * 64 + i * 16 + lr) * BK + kk * 32 + lg * 8];
      #pragma unroll
      for (int i = 0; i < 4; ++i)
        #pragma unroll
        for (int j = 0; j < 4; ++j)
          acc[i][j] = __builtin_amdgcn_mfma_f32_16x16x32_bf16(af[i], bfr[j], acc[i][j], 0, 0, 0);
    }
    __syncthreads();
  }

  // epilogue: C = acc + bias ; C/D layout col=lane&15, row=(lane>>4)*4+reg
  #pragma unroll
  for (int j = 0; j < 4; ++j) {
    const int col = bn * BN + wn * 64 + j * 16 + lr;
    const float bv = bias[col];
    #pragma unroll
    for (int i = 0; i < 4; ++i) {
      const int row0 = bm * BM + wm * 64 + i * 16 + lg * 4;
      #pragma unroll
      for (int rr = 0; rr < 4; ++rr)
        C[(size_t)(row0 + rr) * OUT_ + col] = acc[i][j][rr] + bv;
    }
  }
}

extern "C" void kernel_launch(void* const* d_in, const int* in_sizes, int n_in,
                              void* d_out, int out_size, void* d_ws, size_t ws_size,
                              hipStream_t stream) {
  const float* x  = (const float*)d_in[0];   // [4,4096,2048]
  const float* Wb = (const float*)d_in[1];   // [2048,2048]
  const float* bb = (const float*)d_in[2];   // [2048]
  const float* rW = (const float*)d_in[3];   // [8,2048]
  const float* A  = (const float*)d_in[4];   // [8,16,2048]
  const float* Bw = (const float*)d_in[5];   // [8,2048,16]
  float* out = (float*)d_out;                // [4,4096,2048] fp32

  ushort_t* xext = (ushort_t*)d_ws;                                   // M_ x KX bf16
  ushort_t* wext = (ushort_t*)((char*)d_ws + (size_t)M_ * KX * 2);    // OUT_ x KX bf16

  wprep_kernel<<<OUT_, 256, 0, stream>>>(Wb, Bw, wext);
  xprep_kernel<<<M_, 256, 0, stream>>>(x, rW, A, xext);
  gemm_kernel<<<(M_ / BM) * NT, 256, 0, stream>>>(xext, wext, bb, out);
}

// Round 2
// 390.146 us; speedup vs baseline: 1.0554x; 1.0554x over previous
//
#include <hip/hip_runtime.h>

// Problem constants
#define D_    2048
#define OUT_  2048
#define E_    8
#define R_    16
#define KX    2176          // D_ + E_*R_  (K-extended GEMM depth)
#define M_    16384         // B*S tokens
#define SCALING_F 2.0f      // ALPHA / R = 32/16

typedef unsigned short ushort_t;
typedef unsigned short ushort8 __attribute__((ext_vector_type(8)));
typedef __bf16 bf16x8 __attribute__((ext_vector_type(8)));
typedef float f32x4 __attribute__((ext_vector_type(4)));

__device__ __forceinline__ ushort_t f2bf(float f) {
  unsigned u = __float_as_uint(f);
  u += 0x7FFFu + ((u >> 16) & 1u);   // round-to-nearest-even
  return (ushort_t)(u >> 16);
}

#define GLOAD16(gp, lp)                                                        \
  __builtin_amdgcn_global_load_lds(                                            \
      (const __attribute__((address_space(1))) void*)(gp),                     \
      (__attribute__((address_space(3))) void*)(lp), 16, 0, 0)

// ---------------- W_ext prep: [OUT_][KX] bf16 = bf16(W_base) | Bw[e][o][r] ---
__global__ __launch_bounds__(256) void wprep_kernel(
    const float* __restrict__ W, const float* __restrict__ Bw,
    ushort_t* __restrict__ wext)
{
  const int o = blockIdx.x;     // output row
  const int t = threadIdx.x;    // 0..255
  const float* wr = W + (size_t)o * D_ + t * 8;
  float4 v0 = *(const float4*)wr;
  float4 v1 = *(const float4*)(wr + 4);
  ushort8 wb;
  wb[0] = f2bf(v0.x); wb[1] = f2bf(v0.y); wb[2] = f2bf(v0.z); wb[3] = f2bf(v0.w);
  wb[4] = f2bf(v1.x); wb[5] = f2bf(v1.y); wb[6] = f2bf(v1.z); wb[7] = f2bf(v1.w);
  *(ushort8*)(wext + (size_t)o * KX + t * 8) = wb;
  if (t < E_ * R_) {
    const int e = t >> 4, r = t & 15;
    wext[(size_t)o * KX + D_ + t] = f2bf(Bw[((size_t)e * OUT_ + o) * R_ + r]);
  }
}

// ---------------- router: logits + argmax + bf16 x convert ------------------
// block = 256 thr = 4 waves; each wave handles 4 consecutive tokens.
// rW chunks loaded once per 4 tokens (amortized L2 traffic).
__global__ __launch_bounds__(256) void router_kernel(
    const float* __restrict__ x, const float* __restrict__ rW,
    ushort_t* __restrict__ xext, int* __restrict__ eidx)
{
  const int t = threadIdx.x, lane = t & 63, wid = t >> 6;
  const int m0 = (blockIdx.x * 4 + wid) * 4;   // first of 4 tokens for this wave

  float acc[4][E_];
  #pragma unroll
  for (int k = 0; k < 4; ++k)
    #pragma unroll
    for (int e = 0; e < E_; ++e) acc[k][e] = 0.f;

  #pragma unroll
  for (int j = 0; j < 8; ++j) {
    const int col = j * 256 + lane * 4;
    float4 w[E_];
    #pragma unroll
    for (int e = 0; e < E_; ++e)
      w[e] = *(const float4*)(rW + (size_t)e * D_ + col);
    #pragma unroll
    for (int k = 0; k < 4; ++k) {
      float4 xv = *(const float4*)(x + (size_t)(m0 + k) * D_ + col);
      ushort4 xb;
      xb.x = f2bf(xv.x); xb.y = f2bf(xv.y); xb.z = f2bf(xv.z); xb.w = f2bf(xv.w);
      *(ushort4*)(xext + (size_t)(m0 + k) * KX + col) = xb;
      #pragma unroll
      for (int e = 0; e < E_; ++e)
        acc[k][e] += xv.x * w[e].x + xv.y * w[e].y + xv.z * w[e].z + xv.w * w[e].w;
    }
  }

  // fp64 cross-lane reduce + first-max argmax (matches jnp/np tie-break)
  #pragma unroll
  for (int k = 0; k < 4; ++k) {
    double s0 = acc[k][0], s1 = acc[k][1], s2 = acc[k][2], s3 = acc[k][3];
    double s4 = acc[k][4], s5 = acc[k][5], s6 = acc[k][6], s7 = acc[k][7];
    #pragma unroll
    for (int off = 32; off; off >>= 1) {
      s0 += __shfl_xor(s0, off, 64); s1 += __shfl_xor(s1, off, 64);
      s2 += __shfl_xor(s2, off, 64); s3 += __shfl_xor(s3, off, 64);
      s4 += __shfl_xor(s4, off, 64); s5 += __shfl_xor(s5, off, 64);
      s6 += __shfl_xor(s6, off, 64); s7 += __shfl_xor(s7, off, 64);
    }
    int bi = 0; double best = s0;
    if (s1 > best) { best = s1; bi = 1; }
    if (s2 > best) { best = s2; bi = 2; }
    if (s3 > best) { best = s3; bi = 3; }
    if (s4 > best) { best = s4; bi = 4; }
    if (s5 > best) { best = s5; bi = 5; }
    if (s6 > best) { best = s6; bi = 6; }
    if (s7 > best) { best = s7; bi = 7; }
    if (lane == 0) eidx[m0 + k] = bi;
  }

  // zero the 128 ext cols (hproj overwrites the selected 16)
  if (lane < 32) {
    ushort4 z; z.x = 0; z.y = 0; z.z = 0; z.w = 0;
    #pragma unroll
    for (int k = 0; k < 4; ++k)
      *(ushort4*)(xext + (size_t)(m0 + k) * KX + D_ + lane * 4) = z;
  }
}

// ---------------- h projection: expert-major, A[e] bf16 in LDS --------------
// grid = (M_/HTOK, E_); block 256 = 4 waves; wave-per-token with eidx filter.
#define HTOK 256
__global__ __launch_bounds__(256) void hproj_kernel(
    const ushort_t* __restrict__ xin, const float* __restrict__ A,
    const int* __restrict__ eidx, ushort_t* __restrict__ xext)
{
  __shared__ __attribute__((aligned(16))) ushort_t Ald[R_ * D_];  // 64 KB bf16
  const int t = threadIdx.x, lane = t & 63, wid = t >> 6;
  const int e = blockIdx.y;
  const int mBase = blockIdx.x * HTOK;

  // stage A[e] (16x2048 fp32) -> LDS bf16
  const float* Ae = A + (size_t)e * R_ * D_;
  #pragma unroll
  for (int it = 0; it < 32; ++it) {
    const int idx = it * 1024 + t * 4;
    float4 v = *(const float4*)(Ae + idx);
    ushort4 b;
    b.x = f2bf(v.x); b.y = f2bf(v.y); b.z = f2bf(v.z); b.w = f2bf(v.w);
    *(ushort4*)(Ald + idx) = b;
  }
  __syncthreads();

  for (int m = mBase + wid; m < mBase + HTOK; m += 4) {
    if (eidx[m] != e) continue;          // wave-uniform branch

    // x row bf16: 32 cols/lane, 4 contiguous 1KB chunks
    float xv[32];
    #pragma unroll
    for (int c = 0; c < 4; ++c) {
      bf16x8 xb = *(const bf16x8*)(xin + (size_t)m * KX + c * 512 + lane * 8);
      #pragma unroll
      for (int u = 0; u < 8; ++u) xv[c * 8 + u] = (float)xb[u];
    }
    float h[R_];
    #pragma unroll
    for (int r = 0; r < R_; ++r) {
      float p = 0.f;
      #pragma unroll
      for (int c = 0; c < 4; ++c) {
        bf16x8 ab = *(const bf16x8*)(Ald + r * D_ + c * 512 + lane * 8);
        #pragma unroll
        for (int u = 0; u < 8; ++u) p += xv[c * 8 + u] * (float)ab[u];
      }
      h[r] = p;
    }
    #pragma unroll
    for (int off = 32; off; off >>= 1)
      #pragma unroll
      for (int r = 0; r < R_; ++r)
        h[r] += __shfl_xor(h[r], off, 64);
    if (lane == 0) {
      ushort8 o0, o1;
      #pragma unroll
      for (int u = 0; u < 8; ++u) {
        o0[u] = f2bf(h[u] * SCALING_F);
        o1[u] = f2bf(h[u + 8] * SCALING_F);
      }
      ushort8* dst = (ushort8*)(xext + (size_t)m * KX + D_ + e * R_);
      dst[0] = o0; dst[1] = o1;
    }
  }
}

// ---------------- GEMM: C[M_][OUT_] = Xext @ Wext^T + bias -----------------
// m97 structure: 128x128 tile, BK=64, 4 waves (2x2), global_load_lds width=16
#define BM 128
#define BN 128
#define BK 64
#define NT (OUT_ / BN)   // 16 tiles in N

__global__ __launch_bounds__(256) void gemm_kernel(
    const ushort_t* __restrict__ Ag,   // [M_][KX] bf16
    const ushort_t* __restrict__ Bg,   // [OUT_][KX] bf16
    const float* __restrict__ bias,
    float* __restrict__ C)
{
  __shared__ __attribute__((aligned(16))) ushort_t As[BM * BK];
  __shared__ __attribute__((aligned(16))) ushort_t Bs[BN * BK];

  const int bid = blockIdx.x;
  const int bn = bid & (NT - 1);
  const int bm = bid >> 4;
  const int t = threadIdx.x;
  const int lane = t & 63, w = t >> 6;
  const int wm = w >> 1, wn = w & 1;        // 2x2 wave grid, 64x64 each
  const int lr = lane & 15, lg = lane >> 4; // fragment row / k-group

  f32x4 acc[4][4] = {};

  const size_t aBase = (size_t)(bm * BM) * KX;
  const size_t bBase = (size_t)(bn * BN) * KX;

  for (int k0 = 0; k0 < KX; k0 += BK) {
    #pragma unroll
    for (int j = 0; j < 4; ++j) {
      const int idx = j * 256 + t;
      const int row = idx >> 3;
      const int col = (idx & 7) * 8;
      GLOAD16(Ag + aBase + (size_t)row * KX + k0 + col, (ushort_t*)As + (size_t)idx * 8);
      GLOAD16(Bg + bBase + (size_t)row * KX + k0 + col, (ushort_t*)Bs + (size_t)idx * 8);
    }
    __syncthreads();

    #pragma unroll
    for (int kk = 0; kk < 2; ++kk) {
      bf16x8 af[4], bfr[4];
      #pragma unroll
      for (int i = 0; i < 4; ++i)
        af[i] = *(const bf16x8*)&As[(wm * 64 + i * 16 + lr) * BK + kk * 32 + lg * 8];
      #pragma unroll
      for (int i = 0; i < 4; ++i)
        bfr[i] = *(const bf16x8*)&Bs[(wn * 64 + i * 16 + lr) * BK + kk * 32 + lg * 8];
      #pragma unroll
      for (int i = 0; i < 4; ++i)
        #pragma unroll
        for (int j = 0; j < 4; ++j)
          acc[i][j] = __builtin_amdgcn_mfma_f32_16x16x32_bf16(af[i], bfr[j], acc[i][j], 0, 0, 0);
    }
    __syncthreads();
  }

  #pragma unroll
  for (int j = 0; j < 4; ++j) {
    const int col = bn * BN + wn * 64 + j * 16 + lr;
    const float bv = bias[col];
    #pragma unroll
    for (int i = 0; i < 4; ++i) {
      const int row0 = bm * BM + wm * 64 + i * 16 + lg * 4;
      #pragma unroll
      for (int rr = 0; rr < 4; ++rr)
        C[(size_t)(row0 + rr) * OUT_ + col] = acc[i][j][rr] + bv;
    }
  }
}

extern "C" void kernel_launch(void* const* d_in, const int* in_sizes, int n_in,
                              void* d_out, int out_size, void* d_ws, size_t ws_size,
                              hipStream_t stream) {
  const float* x  = (const float*)d_in[0];   // [4,4096,2048]
  const float* Wb = (const float*)d_in[1];   // [2048,2048]
  const float* bb = (const float*)d_in[2];   // [2048]
  const float* rW = (const float*)d_in[3];   // [8,2048]
  const float* A  = (const float*)d_in[4];   // [8,16,2048]
  const float* Bw = (const float*)d_in[5];   // [8,2048,16]
  float* out = (float*)d_out;                // [4,4096,2048] fp32

  ushort_t* xext = (ushort_t*)d_ws;                                   // M_ x KX bf16
  ushort_t* wext = (ushort_t*)((char*)d_ws + (size_t)M_ * KX * 2);    // OUT_ x KX bf16
  int* eidx = (int*)((char*)d_ws + (size_t)M_ * KX * 2 + (size_t)OUT_ * KX * 2);

  wprep_kernel<<<OUT_, 256, 0, stream>>>(Wb, Bw, wext);
  router_kernel<<<M_ / 16, 256, 0, stream>>>(x, rW, xext, eidx);
  hproj_kernel<<<dim3(M_ / HTOK, E_), 256, 0, stream>>>(xext, A, eidx, xext);
  gemm_kernel<<<(M_ / BM) * NT, 256, 0, stream>>>(xext, wext, bb, out);
}

// Round 3
// 309.689 us; speedup vs baseline: 1.3295x; 1.2598x over previous
//
#include <hip/hip_runtime.h>

// Problem constants
#define D_    2048
#define OUT_  2048
#define E_    8
#define R_    16
#define KX    2176          // D_ + E_*R_  (K-extended GEMM depth)
#define M_    16384         // B*S tokens
#define SCALING_F 2.0f      // ALPHA / R = 32/16

typedef unsigned short ushort_t;
typedef unsigned short ushort8 __attribute__((ext_vector_type(8)));
typedef __bf16 bf16x8 __attribute__((ext_vector_type(8)));
typedef float f32x4 __attribute__((ext_vector_type(4)));

__device__ __forceinline__ ushort_t f2bf(float f) {
  unsigned u = __float_as_uint(f);
  u += 0x7FFFu + ((u >> 16) & 1u);   // round-to-nearest-even
  return (ushort_t)(u >> 16);
}

#define GLOAD16(gp, lp)                                                        \
  __builtin_amdgcn_global_load_lds(                                            \
      (const __attribute__((address_space(1))) void*)(gp),                     \
      (__attribute__((address_space(3))) void*)(lp), 16, 0, 0)

// ---------------- W_ext prep: [OUT_][KX] bf16 = bf16(W_base) | Bw[e][o][r] ---
__global__ __launch_bounds__(256) void wprep_kernel(
    const float* __restrict__ W, const float* __restrict__ Bw,
    ushort_t* __restrict__ wext)
{
  const int o = blockIdx.x;     // output row
  const int t = threadIdx.x;    // 0..255
  const float* wr = W + (size_t)o * D_ + t * 8;
  float4 v0 = *(const float4*)wr;
  float4 v1 = *(const float4*)(wr + 4);
  ushort8 wb;
  wb[0] = f2bf(v0.x); wb[1] = f2bf(v0.y); wb[2] = f2bf(v0.z); wb[3] = f2bf(v0.w);
  wb[4] = f2bf(v1.x); wb[5] = f2bf(v1.y); wb[6] = f2bf(v1.z); wb[7] = f2bf(v1.w);
  *(ushort8*)(wext + (size_t)o * KX + t * 8) = wb;
  if (t < E_ * R_) {
    const int e = t >> 4, r = t & 15;
    wext[(size_t)o * KX + D_ + t] = f2bf(Bw[((size_t)e * OUT_ + o) * R_ + r]);
  }
}

// ---------------- router: logits + argmax + bf16 x convert ------------------
__global__ __launch_bounds__(256) void router_kernel(
    const float* __restrict__ x, const float* __restrict__ rW,
    ushort_t* __restrict__ xext, int* __restrict__ eidx)
{
  const int t = threadIdx.x, lane = t & 63, wid = t >> 6;
  const int m0 = (blockIdx.x * 4 + wid) * 4;   // first of 4 tokens for this wave

  float acc[4][E_];
  #pragma unroll
  for (int k = 0; k < 4; ++k)
    #pragma unroll
    for (int e = 0; e < E_; ++e) acc[k][e] = 0.f;

  #pragma unroll
  for (int j = 0; j < 8; ++j) {
    const int col = j * 256 + lane * 4;
    float4 w[E_];
    #pragma unroll
    for (int e = 0; e < E_; ++e)
      w[e] = *(const float4*)(rW + (size_t)e * D_ + col);
    #pragma unroll
    for (int k = 0; k < 4; ++k) {
      float4 xv = *(const float4*)(x + (size_t)(m0 + k) * D_ + col);
      ushort4 xb;
      xb.x = f2bf(xv.x); xb.y = f2bf(xv.y); xb.z = f2bf(xv.z); xb.w = f2bf(xv.w);
      *(ushort4*)(xext + (size_t)(m0 + k) * KX + col) = xb;
      #pragma unroll
      for (int e = 0; e < E_; ++e)
        acc[k][e] += xv.x * w[e].x + xv.y * w[e].y + xv.z * w[e].z + xv.w * w[e].w;
    }
  }

  #pragma unroll
  for (int k = 0; k < 4; ++k) {
    double s0 = acc[k][0], s1 = acc[k][1], s2 = acc[k][2], s3 = acc[k][3];
    double s4 = acc[k][4], s5 = acc[k][5], s6 = acc[k][6], s7 = acc[k][7];
    #pragma unroll
    for (int off = 32; off; off >>= 1) {
      s0 += __shfl_xor(s0, off, 64); s1 += __shfl_xor(s1, off, 64);
      s2 += __shfl_xor(s2, off, 64); s3 += __shfl_xor(s3, off, 64);
      s4 += __shfl_xor(s4, off, 64); s5 += __shfl_xor(s5, off, 64);
      s6 += __shfl_xor(s6, off, 64); s7 += __shfl_xor(s7, off, 64);
    }
    int bi = 0; double best = s0;
    if (s1 > best) { best = s1; bi = 1; }
    if (s2 > best) { best = s2; bi = 2; }
    if (s3 > best) { best = s3; bi = 3; }
    if (s4 > best) { best = s4; bi = 4; }
    if (s5 > best) { best = s5; bi = 5; }
    if (s6 > best) { best = s6; bi = 6; }
    if (s7 > best) { best = s7; bi = 7; }
    if (lane == 0) eidx[m0 + k] = bi;
  }

  if (lane < 32) {
    ushort4 z; z.x = 0; z.y = 0; z.z = 0; z.w = 0;
    #pragma unroll
    for (int k = 0; k < 4; ++k)
      *(ushort4*)(xext + (size_t)(m0 + k) * KX + D_ + lane * 4) = z;
  }
}

// ---------------- h projection: expert-major, A[e] bf16 in LDS --------------
#define HTOK 256
__global__ __launch_bounds__(256) void hproj_kernel(
    const ushort_t* __restrict__ xin, const float* __restrict__ A,
    const int* __restrict__ eidx, ushort_t* __restrict__ xext)
{
  __shared__ __attribute__((aligned(16))) ushort_t Ald[R_ * D_];  // 64 KB bf16
  const int t = threadIdx.x, lane = t & 63, wid = t >> 6;
  const int e = blockIdx.y;
  const int mBase = blockIdx.x * HTOK;

  const float* Ae = A + (size_t)e * R_ * D_;
  #pragma unroll
  for (int it = 0; it < 32; ++it) {
    const int idx = it * 1024 + t * 4;
    float4 v = *(const float4*)(Ae + idx);
    ushort4 b;
    b.x = f2bf(v.x); b.y = f2bf(v.y); b.z = f2bf(v.z); b.w = f2bf(v.w);
    *(ushort4*)(Ald + idx) = b;
  }
  __syncthreads();

  for (int m = mBase + wid; m < mBase + HTOK; m += 4) {
    if (eidx[m] != e) continue;          // wave-uniform branch

    float xv[32];
    #pragma unroll
    for (int c = 0; c < 4; ++c) {
      bf16x8 xb = *(const bf16x8*)(xin + (size_t)m * KX + c * 512 + lane * 8);
      #pragma unroll
      for (int u = 0; u < 8; ++u) xv[c * 8 + u] = (float)xb[u];
    }
    float h[R_];
    #pragma unroll
    for (int r = 0; r < R_; ++r) {
      float p = 0.f;
      #pragma unroll
      for (int c = 0; c < 4; ++c) {
        bf16x8 ab = *(const bf16x8*)(Ald + r * D_ + c * 512 + lane * 8);
        #pragma unroll
        for (int u = 0; u < 8; ++u) p += xv[c * 8 + u] * (float)ab[u];
      }
      h[r] = p;
    }
    #pragma unroll
    for (int off = 32; off; off >>= 1)
      #pragma unroll
      for (int r = 0; r < R_; ++r)
        h[r] += __shfl_xor(h[r], off, 64);
    if (lane == 0) {
      ushort8 o0, o1;
      #pragma unroll
      for (int u = 0; u < 8; ++u) {
        o0[u] = f2bf(h[u] * SCALING_F);
        o1[u] = f2bf(h[u + 8] * SCALING_F);
      }
      ushort8* dst = (ushort8*)(xext + (size_t)m * KX + D_ + e * R_);
      dst[0] = o0; dst[1] = o1;
    }
  }
}

// ---------------- GEMM: 256x256 tile, 8-phase schedule (m201 template) ------
// BM=BN=256, BK=64, 8 waves (2Mx4N), 512 thr, 128 KiB LDS double-buffer.
// T2 st-swizzle (slot^row&7 both sides), counted vmcnt(2)/K-tile, setprio.
#define NKT (KX / 64)        // 34 K-tiles
#define NSTG (NKT * 4)       // 136 half-tile stages

__global__ __launch_bounds__(512, 2) void gemm_kernel(
    const ushort_t* __restrict__ Ag,   // [M_][KX] bf16
    const ushort_t* __restrict__ Bg,   // [OUT_][KX] bf16
    const float* __restrict__ bias,
    float* __restrict__ C)
{
  __shared__ __attribute__((aligned(16))) char lds[131072];

  const int t = threadIdx.x;
  const int lane = t & 63, w = t >> 6;
  const int wm = w >> 2, wn = w & 3;          // 2x4 wave grid; wave tile 128x64
  const int lr = lane & 15, lg = lane >> 4;
  const int koff = (lr & 7) << 4;             // read-side swizzle XOR (bytes)

  // XCD-bijective blockIdx swizzle (512 % 8 == 0)
  const int swz = (blockIdx.x & 7) * 64 + (blockIdx.x >> 3);
  const int bm = swz >> 3, bn = swz & 7;

  // staging constants: thread t covers row (g*64 + t>>3), slot (t&7)
  const int sg_row = t >> 3;
  const int sg_slotx = (t & 7) ^ ((t >> 3) & 7);   // pre-swizzled source slot
  const size_t aRow0 = (size_t)bm * 256;
  const size_t bRow0 = (size_t)bn * 256;

  // stage half-tile s: tile TT=s>>2, j=s&3 (0,1 = A halves; 2,3 = B halves)
  auto stage = [&](int s) {
    if (s >= NSTG) return;
    const int TT = s >> 2, j = s & 3;
    const int isB = j >> 1, half = j & 1;
    const ushort_t* src = isB ? Bg : Ag;
    const size_t gr0 = (isB ? bRow0 : aRow0) + half * 128;
    char* dst = lds + (TT & 1) * 65536 + isB * 32768 + half * 16384;
    #pragma unroll
    for (int g = 0; g < 2; ++g) {
      const int r = g * 64 + sg_row;
      GLOAD16(src + (gr0 + r) * KX + TT * 64 + sg_slotx * 8,
              dst + g * 8192 + t * 16);
    }
  };

  f32x4 acc[8][4] = {};
  bf16x8 bq[4][2];

  // prologue: tile 0 (s=0..3) + (1,0); wait tile 0 landed, (1,0) in flight
  stage(0); stage(1); stage(2); stage(3); stage(4);
  asm volatile("s_waitcnt vmcnt(2)" ::: "memory");
  __builtin_amdgcn_s_barrier();

  #pragma unroll 2
  for (int T = 0; T < NKT; ++T) {
    char* Ab = lds + (T & 1) * 65536;
    char* Bb = Ab + 32768;
    #pragma unroll
    for (int q = 0; q < 4; ++q) {
      // --- ds-load register subtile ---
      bf16x8 aq[2][2];
      if (q == 0) {
        #pragma unroll
        for (int nj = 0; nj < 4; ++nj) {
          const int R = wn * 64 + nj * 16 + lr;
          #pragma unroll
          for (int kk = 0; kk < 2; ++kk)
            bq[nj][kk] = *(const bf16x8*)(Bb + R * 128 + ((kk * 64 + lg * 16) ^ koff));
        }
      }
      #pragma unroll
      for (int i = 0; i < 2; ++i) {
        const int R = wm * 128 + (q * 2 + i) * 16 + lr;
        #pragma unroll
        for (int kk = 0; kk < 2; ++kk)
          aq[i][kk] = *(const bf16x8*)(Ab + R * 128 + ((kk * 64 + lg * 16) ^ koff));
      }
      // --- stage 1 half-tile: s = 4T+5+q -> (T+1,q+1) for q<3, (T+2,0) at q=3
      stage(4 * T + 5 + q);
      if (q == 0) asm volatile("s_waitcnt lgkmcnt(8)" ::: "memory");
      __builtin_amdgcn_s_barrier();
      asm volatile("s_waitcnt lgkmcnt(0)" ::: "memory");
      // --- MFMA cluster: one C-quadrant (2 m-frags x 4 n-frags) x K=64 ---
      __builtin_amdgcn_s_setprio(1);
      #pragma unroll
      for (int i = 0; i < 2; ++i)
        #pragma unroll
        for (int nj = 0; nj < 4; ++nj)
          #pragma unroll
          for (int kk = 0; kk < 2; ++kk)
            acc[q * 2 + i][nj] = __builtin_amdgcn_mfma_f32_16x16x32_bf16(
                aq[i][kk], bq[nj][kk], acc[q * 2 + i][nj], 0, 0, 0);
      __builtin_amdgcn_s_setprio(0);
      if (q == 3) {
        if (T >= NKT - 2) asm volatile("s_waitcnt vmcnt(0)" ::: "memory");
        else              asm volatile("s_waitcnt vmcnt(2)" ::: "memory");
      }
      __builtin_amdgcn_s_barrier();
    }
  }

  // epilogue: C = acc + bias ; C/D layout col=lane&15, row=(lane>>4)*4+reg
  #pragma unroll
  for (int nj = 0; nj < 4; ++nj) {
    const int col = bn * 256 + wn * 64 + nj * 16 + lr;
    const float bv = bias[col];
    #pragma unroll
    for (int mi = 0; mi < 8; ++mi) {
      const int row0 = bm * 256 + wm * 128 + mi * 16 + lg * 4;
      #pragma unroll
      for (int rr = 0; rr < 4; ++rr)
        C[(size_t)(row0 + rr) * OUT_ + col] = acc[mi][nj][rr] + bv;
    }
  }
}

extern "C" void kernel_launch(void* const* d_in, const int* in_sizes, int n_in,
                              void* d_out, int out_size, void* d_ws, size_t ws_size,
                              hipStream_t stream) {
  const float* x  = (const float*)d_in[0];   // [4,4096,2048]
  const float* Wb = (const float*)d_in[1];   // [2048,2048]
  const float* bb = (const float*)d_in[2];   // [2048]
  const float* rW = (const float*)d_in[3];   // [8,2048]
  const float* A  = (const float*)d_in[4];   // [8,16,2048]
  const float* Bw = (const float*)d_in[5];   // [8,2048,16]
  float* out = (float*)d_out;                // [4,4096,2048] fp32

  ushort_t* xext = (ushort_t*)d_ws;                                   // M_ x KX bf16
  ushort_t* wext = (ushort_t*)((char*)d_ws + (size_t)M_ * KX * 2);    // OUT_ x KX bf16
  int* eidx = (int*)((char*)d_ws + (size_t)M_ * KX * 2 + (size_t)OUT_ * KX * 2);

  wprep_kernel<<<OUT_, 256, 0, stream>>>(Wb, Bw, wext);
  router_kernel<<<M_ / 16, 256, 0, stream>>>(x, rW, xext, eidx);
  hproj_kernel<<<dim3(M_ / HTOK, E_), 256, 0, stream>>>(xext, A, eidx, xext);
  gemm_kernel<<<(M_ / 256) * (OUT_ / 256), 512, 0, stream>>>(xext, wext, bb, out);
}

// Round 4
// 267.941 us; speedup vs baseline: 1.5367x; 1.1558x over previous
//
#include <hip/hip_runtime.h>

// Problem constants
#define D_    2048
#define OUT_  2048
#define E_    8
#define R_    16
#define KX    2176          // D_ + E_*R_  (K-extended GEMM depth)
#define M_    16384         // B*S tokens
#define SCALING_F 2.0f      // ALPHA / R = 32/16

typedef unsigned short ushort_t;
typedef unsigned short ushort8 __attribute__((ext_vector_type(8)));
typedef __bf16 bf16x8 __attribute__((ext_vector_type(8)));
typedef float f32x4 __attribute__((ext_vector_type(4)));

__device__ __forceinline__ ushort_t f2bf(float f) {
  unsigned u = __float_as_uint(f);
  u += 0x7FFFu + ((u >> 16) & 1u);   // round-to-nearest-even
  return (ushort_t)(u >> 16);
}

#define GLOAD16(gp, lp)                                                        \
  __builtin_amdgcn_global_load_lds(                                            \
      (const __attribute__((address_space(1))) void*)(gp),                     \
      (__attribute__((address_space(3))) void*)(lp), 16, 0, 0)

// ---------------- W_ext prep: [OUT_][KX] bf16 = bf16(W_base) | Bw[e][o][r] ---
__global__ __launch_bounds__(256) void wprep_kernel(
    const float* __restrict__ W, const float* __restrict__ Bw,
    ushort_t* __restrict__ wext)
{
  const int o = blockIdx.x;     // output row
  const int t = threadIdx.x;    // 0..255
  const float* wr = W + (size_t)o * D_ + t * 8;
  float4 v0 = *(const float4*)wr;
  float4 v1 = *(const float4*)(wr + 4);
  ushort8 wb;
  wb[0] = f2bf(v0.x); wb[1] = f2bf(v0.y); wb[2] = f2bf(v0.z); wb[3] = f2bf(v0.w);
  wb[4] = f2bf(v1.x); wb[5] = f2bf(v1.y); wb[6] = f2bf(v1.z); wb[7] = f2bf(v1.w);
  *(ushort8*)(wext + (size_t)o * KX + t * 8) = wb;
  if (t < E_ * R_) {
    const int e = t >> 4, r = t & 15;
    wext[(size_t)o * KX + D_ + t] = f2bf(Bw[((size_t)e * OUT_ + o) * R_ + r]);
  }
}

// ---------------- A prep: [E*R=128][D_] fp32 -> bf16 ------------------------
__global__ __launch_bounds__(256) void aprep_kernel(
    const float* __restrict__ A, ushort_t* __restrict__ aext)
{
  const size_t i = ((size_t)blockIdx.x * 256 + threadIdx.x) * 8;
  float4 v0 = *(const float4*)(A + i);
  float4 v1 = *(const float4*)(A + i + 4);
  ushort8 b;
  b[0] = f2bf(v0.x); b[1] = f2bf(v0.y); b[2] = f2bf(v0.z); b[3] = f2bf(v0.w);
  b[4] = f2bf(v1.x); b[5] = f2bf(v1.y); b[6] = f2bf(v1.z); b[7] = f2bf(v1.w);
  *(ushort8*)(aext + i) = b;
}

// ---------------- router: logits + argmax + bf16 x convert ------------------
__global__ __launch_bounds__(256) void router_kernel(
    const float* __restrict__ x, const float* __restrict__ rW,
    ushort_t* __restrict__ xext, int* __restrict__ eidx)
{
  const int t = threadIdx.x, lane = t & 63, wid = t >> 6;
  const int m0 = (blockIdx.x * 4 + wid) * 4;   // first of 4 tokens for this wave

  float acc[4][E_];
  #pragma unroll
  for (int k = 0; k < 4; ++k)
    #pragma unroll
    for (int e = 0; e < E_; ++e) acc[k][e] = 0.f;

  #pragma unroll
  for (int j = 0; j < 8; ++j) {
    const int col = j * 256 + lane * 4;
    float4 w[E_];
    #pragma unroll
    for (int e = 0; e < E_; ++e)
      w[e] = *(const float4*)(rW + (size_t)e * D_ + col);
    #pragma unroll
    for (int k = 0; k < 4; ++k) {
      float4 xv = *(const float4*)(x + (size_t)(m0 + k) * D_ + col);
      ushort4 xb;
      xb.x = f2bf(xv.x); xb.y = f2bf(xv.y); xb.z = f2bf(xv.z); xb.w = f2bf(xv.w);
      *(ushort4*)(xext + (size_t)(m0 + k) * KX + col) = xb;
      #pragma unroll
      for (int e = 0; e < E_; ++e)
        acc[k][e] += xv.x * w[e].x + xv.y * w[e].y + xv.z * w[e].z + xv.w * w[e].w;
    }
  }

  #pragma unroll
  for (int k = 0; k < 4; ++k) {
    double s0 = acc[k][0], s1 = acc[k][1], s2 = acc[k][2], s3 = acc[k][3];
    double s4 = acc[k][4], s5 = acc[k][5], s6 = acc[k][6], s7 = acc[k][7];
    #pragma unroll
    for (int off = 32; off; off >>= 1) {
      s0 += __shfl_xor(s0, off, 64); s1 += __shfl_xor(s1, off, 64);
      s2 += __shfl_xor(s2, off, 64); s3 += __shfl_xor(s3, off, 64);
      s4 += __shfl_xor(s4, off, 64); s5 += __shfl_xor(s5, off, 64);
      s6 += __shfl_xor(s6, off, 64); s7 += __shfl_xor(s7, off, 64);
    }
    int bi = 0; double best = s0;
    if (s1 > best) { best = s1; bi = 1; }
    if (s2 > best) { best = s2; bi = 2; }
    if (s3 > best) { best = s3; bi = 3; }
    if (s4 > best) { best = s4; bi = 4; }
    if (s5 > best) { best = s5; bi = 5; }
    if (s6 > best) { best = s6; bi = 6; }
    if (s7 > best) { best = s7; bi = 7; }
    if (lane == 0) eidx[m0 + k] = bi;
  }
}

// ---------------- h GEMM: h_all = Xbf @ Aext^T, masked write into xext ------
// M=16384, N=128, K=2048. BM=32, grid 512. 4 waves (2x2), wave tile 16x64.
// 2-phase double-buffered global_load_lds; T2 slot^row&7 swizzle both sides.
#define HG_NKT (D_ / 64)     // 32 K-tiles

__global__ __launch_bounds__(256) void hgemm_kernel(
    const ushort_t* __restrict__ Xg,   // [M_][KX] bf16 (reads cols 0..D_)
    const ushort_t* __restrict__ Ae,   // [128][D_] bf16
    const int* __restrict__ eidx,
    ushort_t* __restrict__ xext)       // writes cols D_..KX
{
  __shared__ __attribute__((aligned(16))) char lds[40960];  // 2 x (4KB A + 16KB B)

  const int t = threadIdx.x;
  const int lane = t & 63, w = t >> 6;
  const int wr = w >> 1, wc = w & 1;          // wave tile 16 rows x 64 cols
  const int lr = lane & 15, lg = lane >> 4;
  const int koff = (lr & 7) << 4;

  const int bm = blockIdx.x;                   // 512 blocks x 32 rows
  const size_t row0 = (size_t)bm * 32;

  const int sg_row = t >> 3;                   // 0..31
  const int sg_slotx = (t & 7) ^ ((t >> 3) & 7);

  auto stage = [&](int TT) {
    char* dst = lds + (TT & 1) * 20480;
    // A: 32 rows x 64 cols (one gload per thread)
    GLOAD16(Xg + (row0 + sg_row) * KX + TT * 64 + sg_slotx * 8, dst + t * 16);
    // B: 128 rows x 64 cols
    #pragma unroll
    for (int g = 0; g < 4; ++g) {
      const int r = g * 32 + sg_row;
      GLOAD16(Ae + (size_t)r * D_ + TT * 64 + sg_slotx * 8,
              dst + 4096 + g * 4096 + t * 16);
    }
  };

  f32x4 acc[4] = {};

  stage(0);
  asm volatile("s_waitcnt vmcnt(0)" ::: "memory");
  __builtin_amdgcn_s_barrier();

  for (int T = 0; T < HG_NKT; ++T) {
    if (T + 1 < HG_NKT) stage(T + 1);
    char* Ab = lds + (T & 1) * 20480;
    char* Bb = Ab + 4096;
    bf16x8 af[2], bfr[4][2];
    #pragma unroll
    for (int kk = 0; kk < 2; ++kk)
      af[kk] = *(const bf16x8*)(Ab + (wr * 16 + lr) * 128 + ((kk * 64 + lg * 16) ^ koff));
    #pragma unroll
    for (int nj = 0; nj < 4; ++nj) {
      const int R = wc * 64 + nj * 16 + lr;
      #pragma unroll
      for (int kk = 0; kk < 2; ++kk)
        bfr[nj][kk] = *(const bf16x8*)(Bb + R * 128 + ((kk * 64 + lg * 16) ^ koff));
    }
    #pragma unroll
    for (int nj = 0; nj < 4; ++nj)
      #pragma unroll
      for (int kk = 0; kk < 2; ++kk)
        acc[nj] = __builtin_amdgcn_mfma_f32_16x16x32_bf16(af[kk], bfr[nj][kk], acc[nj], 0, 0, 0);
    asm volatile("s_waitcnt vmcnt(0)" ::: "memory");
    __builtin_amdgcn_s_barrier();
  }

  // masked epilogue: xext[row][D_+col] = (eidx[row]==col>>4) ? bf16(2*h) : 0
  int er[4];
  #pragma unroll
  for (int rr = 0; rr < 4; ++rr)
    er[rr] = eidx[row0 + wr * 16 + lg * 4 + rr];
  #pragma unroll
  for (int nj = 0; nj < 4; ++nj) {
    const int col = wc * 64 + nj * 16 + lr;
    const int ecol = wc * 4 + nj;              // col>>4, wave-uniform per nj
    #pragma unroll
    for (int rr = 0; rr < 4; ++rr) {
      const size_t row = row0 + wr * 16 + lg * 4 + rr;
      ushort_t v = (er[rr] == ecol) ? f2bf(acc[nj][rr] * SCALING_F) : (ushort_t)0;
      xext[row * KX + D_ + col] = v;
    }
  }
}

// ---------------- GEMM: 256x256 tile, 8-phase schedule (m201 template) ------
// BM=BN=256, BK=64, 8 waves (2Mx4N), 512 thr, 128 KiB LDS double-buffer.
// T2 st-swizzle (slot^row&7 both sides), counted vmcnt(2)/K-tile, setprio.
#define NKT (KX / 64)        // 34 K-tiles
#define NSTG (NKT * 4)       // 136 half-tile stages

__global__ __launch_bounds__(512, 2) void gemm_kernel(
    const ushort_t* __restrict__ Ag,   // [M_][KX] bf16
    const ushort_t* __restrict__ Bg,   // [OUT_][KX] bf16
    const float* __restrict__ bias,
    float* __restrict__ C)
{
  __shared__ __attribute__((aligned(16))) char lds[131072];

  const int t = threadIdx.x;
  const int lane = t & 63, w = t >> 6;
  const int wm = w >> 2, wn = w & 3;          // 2x4 wave grid; wave tile 128x64
  const int lr = lane & 15, lg = lane >> 4;
  const int koff = (lr & 7) << 4;             // read-side swizzle XOR (bytes)

  // XCD-bijective blockIdx swizzle (512 % 8 == 0)
  const int swz = (blockIdx.x & 7) * 64 + (blockIdx.x >> 3);
  const int bm = swz >> 3, bn = swz & 7;

  // staging constants: thread t covers row (g*64 + t>>3), slot (t&7)
  const int sg_row = t >> 3;
  const int sg_slotx = (t & 7) ^ ((t >> 3) & 7);   // pre-swizzled source slot
  const size_t aRow0 = (size_t)bm * 256;
  const size_t bRow0 = (size_t)bn * 256;

  // stage half-tile s: tile TT=s>>2, j=s&3 (0,1 = A halves; 2,3 = B halves)
  auto stage = [&](int s) {
    if (s >= NSTG) return;
    const int TT = s >> 2, j = s & 3;
    const int isB = j >> 1, half = j & 1;
    const ushort_t* src = isB ? Bg : Ag;
    const size_t gr0 = (isB ? bRow0 : aRow0) + half * 128;
    char* dst = lds + (TT & 1) * 65536 + isB * 32768 + half * 16384;
    #pragma unroll
    for (int g = 0; g < 2; ++g) {
      const int r = g * 64 + sg_row;
      GLOAD16(src + (gr0 + r) * KX + TT * 64 + sg_slotx * 8,
              dst + g * 8192 + t * 16);
    }
  };

  f32x4 acc[8][4] = {};
  bf16x8 bq[4][2];

  // prologue: tile 0 (s=0..3) + (1,0); wait tile 0 landed, (1,0) in flight
  stage(0); stage(1); stage(2); stage(3); stage(4);
  asm volatile("s_waitcnt vmcnt(2)" ::: "memory");
  __builtin_amdgcn_s_barrier();

  #pragma unroll 2
  for (int T = 0; T < NKT; ++T) {
    char* Ab = lds + (T & 1) * 65536;
    char* Bb = Ab + 32768;
    #pragma unroll
    for (int q = 0; q < 4; ++q) {
      // --- ds-load register subtile ---
      bf16x8 aq[2][2];
      if (q == 0) {
        #pragma unroll
        for (int nj = 0; nj < 4; ++nj) {
          const int R = wn * 64 + nj * 16 + lr;
          #pragma unroll
          for (int kk = 0; kk < 2; ++kk)
            bq[nj][kk] = *(const bf16x8*)(Bb + R * 128 + ((kk * 64 + lg * 16) ^ koff));
        }
      }
      #pragma unroll
      for (int i = 0; i < 2; ++i) {
        const int R = wm * 128 + (q * 2 + i) * 16 + lr;
        #pragma unroll
        for (int kk = 0; kk < 2; ++kk)
          aq[i][kk] = *(const bf16x8*)(Ab + R * 128 + ((kk * 64 + lg * 16) ^ koff));
      }
      // --- stage 1 half-tile: s = 4T+5+q -> (T+1,q+1) for q<3, (T+2,0) at q=3
      stage(4 * T + 5 + q);
      if (q == 0) asm volatile("s_waitcnt lgkmcnt(8)" ::: "memory");
      __builtin_amdgcn_s_barrier();
      asm volatile("s_waitcnt lgkmcnt(0)" ::: "memory");
      // --- MFMA cluster: one C-quadrant (2 m-frags x 4 n-frags) x K=64 ---
      __builtin_amdgcn_s_setprio(1);
      #pragma unroll
      for (int i = 0; i < 2; ++i)
        #pragma unroll
        for (int nj = 0; nj < 4; ++nj)
          #pragma unroll
          for (int kk = 0; kk < 2; ++kk)
            acc[q * 2 + i][nj] = __builtin_amdgcn_mfma_f32_16x16x32_bf16(
                aq[i][kk], bq[nj][kk], acc[q * 2 + i][nj], 0, 0, 0);
      __builtin_amdgcn_s_setprio(0);
      if (q == 3) {
        if (T >= NKT - 2) asm volatile("s_waitcnt vmcnt(0)" ::: "memory");
        else              asm volatile("s_waitcnt vmcnt(2)" ::: "memory");
      }
      __builtin_amdgcn_s_barrier();
    }
  }

  // epilogue: C = acc + bias ; C/D layout col=lane&15, row=(lane>>4)*4+reg
  #pragma unroll
  for (int nj = 0; nj < 4; ++nj) {
    const int col = bn * 256 + wn * 64 + nj * 16 + lr;
    const float bv = bias[col];
    #pragma unroll
    for (int mi = 0; mi < 8; ++mi) {
      const int row0 = bm * 256 + wm * 128 + mi * 16 + lg * 4;
      #pragma unroll
      for (int rr = 0; rr < 4; ++rr)
        C[(size_t)(row0 + rr) * OUT_ + col] = acc[mi][nj][rr] + bv;
    }
  }
}

extern "C" void kernel_launch(void* const* d_in, const int* in_sizes, int n_in,
                              void* d_out, int out_size, void* d_ws, size_t ws_size,
                              hipStream_t stream) {
  const float* x  = (const float*)d_in[0];   // [4,4096,2048]
  const float* Wb = (const float*)d_in[1];   // [2048,2048]
  const float* bb = (const float*)d_in[2];   // [2048]
  const float* rW = (const float*)d_in[3];   // [8,2048]
  const float* A  = (const float*)d_in[4];   // [8,16,2048]
  const float* Bw = (const float*)d_in[5];   // [8,2048,16]
  float* out = (float*)d_out;                // [4,4096,2048] fp32

  ushort_t* xext = (ushort_t*)d_ws;                                   // M_ x KX bf16
  ushort_t* wext = (ushort_t*)((char*)d_ws + (size_t)M_ * KX * 2);    // OUT_ x KX bf16
  int* eidx = (int*)((char*)d_ws + (size_t)M_ * KX * 2 + (size_t)OUT_ * KX * 2);
  ushort_t* aext = (ushort_t*)((char*)eidx + M_ * sizeof(int));       // 128 x D_ bf16

  wprep_kernel<<<OUT_, 256, 0, stream>>>(Wb, Bw, wext);
  aprep_kernel<<<(E_ * R_ * D_) / (256 * 8), 256, 0, stream>>>(A, aext);
  router_kernel<<<M_ / 16, 256, 0, stream>>>(x, rW, xext, eidx);
  hgemm_kernel<<<M_ / 32, 256, 0, stream>>>(xext, aext, eidx, xext);
  gemm_kernel<<<(M_ / 256) * (OUT_ / 256), 512, 0, stream>>>(xext, wext, bb, out);
}

// Round 6
// 245.533 us; speedup vs baseline: 1.6769x; 1.0913x over previous
//
#include <hip/hip_runtime.h>

// Problem constants
#define D_    2048
#define OUT_  2048
#define E_    8
#define R_    16
#define KX    2176          // D_ + E_*R_  (K-extended GEMM depth)
#define M_    16384         // B*S tokens
#define SCALING_F 2.0f      // ALPHA / R = 32/16

typedef unsigned short ushort_t;
typedef unsigned short ushort8 __attribute__((ext_vector_type(8)));
typedef __bf16 bf16x8 __attribute__((ext_vector_type(8)));
typedef float f32x4 __attribute__((ext_vector_type(4)));

__device__ __forceinline__ ushort_t f2bf(float f) {
  unsigned u = __float_as_uint(f);
  u += 0x7FFFu + ((u >> 16) & 1u);   // round-to-nearest-even
  return (ushort_t)(u >> 16);
}

#define GLOAD16(gp, lp)                                                        \
  __builtin_amdgcn_global_load_lds(                                            \
      (const __attribute__((address_space(1))) void*)(gp),                     \
      (__attribute__((address_space(3))) void*)(lp), 16, 0, 0)

// -------- W_ext + A_ext prep (fused): wext[OUT_][KX], aext[128][D_] bf16 ----
__global__ __launch_bounds__(256) void wprep_all_kernel(
    const float* __restrict__ W, const float* __restrict__ Bw,
    const float* __restrict__ A,
    ushort_t* __restrict__ wext, ushort_t* __restrict__ aext)
{
  const int bid = blockIdx.x;
  const int t = threadIdx.x;
  if (bid < OUT_) {
    const int o = bid;
    const float* wr = W + (size_t)o * D_ + t * 8;
    float4 v0 = *(const float4*)wr;
    float4 v1 = *(const float4*)(wr + 4);
    ushort8 wb;
    wb[0] = f2bf(v0.x); wb[1] = f2bf(v0.y); wb[2] = f2bf(v0.z); wb[3] = f2bf(v0.w);
    wb[4] = f2bf(v1.x); wb[5] = f2bf(v1.y); wb[6] = f2bf(v1.z); wb[7] = f2bf(v1.w);
    *(ushort8*)(wext + (size_t)o * KX + t * 8) = wb;
    if (t < E_ * R_) {
      const int e = t >> 4, r = t & 15;
      wext[(size_t)o * KX + D_ + t] = f2bf(Bw[((size_t)e * OUT_ + o) * R_ + r]);
    }
  } else {
    const size_t i = ((size_t)(bid - OUT_) * 256 + t) * 8;
    float4 v0 = *(const float4*)(A + i);
    float4 v1 = *(const float4*)(A + i + 4);
    ushort8 b;
    b[0] = f2bf(v0.x); b[1] = f2bf(v0.y); b[2] = f2bf(v0.z); b[3] = f2bf(v0.w);
    b[4] = f2bf(v1.x); b[5] = f2bf(v1.y); b[6] = f2bf(v1.z); b[7] = f2bf(v1.w);
    *(ushort8*)(aext + i) = b;
  }
}

// ---------------- router: logits + argmax only (no xext writes) -------------
// 4 tokens/wave; fp32 xor1/2/4 reduce then fp64 xor8/16/32 (argmax precision).
__global__ __launch_bounds__(256) void router_kernel(
    const float* __restrict__ x, const float* __restrict__ rW,
    int* __restrict__ eidx)
{
  const int t = threadIdx.x, lane = t & 63, wid = t >> 6;
  const int m0 = (blockIdx.x * 4 + wid) * 4;   // first of 4 tokens for this wave

  float acc[4][E_];
  #pragma unroll
  for (int k = 0; k < 4; ++k)
    #pragma unroll
    for (int e = 0; e < E_; ++e) acc[k][e] = 0.f;

  #pragma unroll
  for (int j = 0; j < 8; ++j) {
    const int col = j * 256 + lane * 4;
    float4 w[E_];
    #pragma unroll
    for (int e = 0; e < E_; ++e)
      w[e] = *(const float4*)(rW + (size_t)e * D_ + col);
    #pragma unroll
    for (int k = 0; k < 4; ++k) {
      float4 xv = *(const float4*)(x + (size_t)(m0 + k) * D_ + col);
      #pragma unroll
      for (int e = 0; e < E_; ++e)
        acc[k][e] += xv.x * w[e].x + xv.y * w[e].y + xv.z * w[e].z + xv.w * w[e].w;
    }
  }

  #pragma unroll
  for (int k = 0; k < 4; ++k) {
    float r[E_];
    #pragma unroll
    for (int e = 0; e < E_; ++e) r[e] = acc[k][e];
    #pragma unroll
    for (int off = 1; off <= 4; off <<= 1)
      #pragma unroll
      for (int e = 0; e < E_; ++e) r[e] += __shfl_xor(r[e], off, 64);
    double s[E_];
    #pragma unroll
    for (int e = 0; e < E_; ++e) s[e] = (double)r[e];
    #pragma unroll
    for (int off = 8; off <= 32; off <<= 1)
      #pragma unroll
      for (int e = 0; e < E_; ++e) s[e] += __shfl_xor(s[e], off, 64);
    int bi = 0; double best = s[0];
    #pragma unroll
    for (int e = 1; e < E_; ++e)
      if (s[e] > best) { best = s[e]; bi = e; }   // first-max tie-break
    if (lane == 0) eidx[m0 + k] = bi;
  }
}

// ------- h GEMM + x convert (fused): reads x fp32, writes FULL xext row -----
// Per block: 32 token rows. Per K-tile: reg-load x fp32 -> cvt bf16 ->
// {global store xext core, swizzled ds_write Xb} ; gload_lds Ae tile.
// MFMA h_all = Xb @ Ab^T (M=32,N=128); masked epilogue writes ext cols.
// Race-safety: stageA/putX target buffer (TT&1) == NOT the buffer being read
// this iteration; __syncthreads() full-drains vmcnt+lgkmcnt each iteration.
#define HG_NKT (D_ / 64)     // 32 K-tiles

__global__ __launch_bounds__(256) void hgemm_kernel(
    const float* __restrict__ x,       // [M_][D_] fp32
    const ushort_t* __restrict__ Ae,   // [128][D_] bf16
    const int* __restrict__ eidx,
    ushort_t* __restrict__ xext)       // writes all KX cols
{
  __shared__ __attribute__((aligned(16))) char lds[40960];  // 2 x (4KB X + 16KB A)

  const int t = threadIdx.x;
  const int lane = t & 63, w = t >> 6;
  const int wr = w >> 1, wc = w & 1;          // wave tile 16 rows x 64 cols
  const int lr = lane & 15, lg = lane >> 4;
  const int koff = (lr & 7) << 4;

  const int bm = blockIdx.x;                   // 512 blocks x 32 rows
  const size_t row0 = (size_t)bm * 32;

  const int sg_row = t >> 3;                   // 0..31
  const int sg_c = t & 7;                      // col chunk (8 bf16)
  const int sg_slotx = sg_c ^ (sg_row & 7);    // pre-swizzled slot

  // stage Ae tile TT into buffer (TT&1): 128 rows x 64 cols bf16
  auto stageA = [&](int TT) {
    char* dst = lds + (TT & 1) * 20480 + 4096;
    #pragma unroll
    for (int g = 0; g < 4; ++g) {
      const int r = g * 32 + sg_row;
      GLOAD16(Ae + (size_t)r * D_ + TT * 64 + sg_slotx * 8,
              dst + g * 4096 + t * 16);
    }
  };
  // convert 8 x-floats and write LDS (swizzled) + global xext core
  auto putX = [&](int TT, const float4& a, const float4& b) {
    ushort8 xb;
    xb[0] = f2bf(a.x); xb[1] = f2bf(a.y); xb[2] = f2bf(a.z); xb[3] = f2bf(a.w);
    xb[4] = f2bf(b.x); xb[5] = f2bf(b.y); xb[6] = f2bf(b.z); xb[7] = f2bf(b.w);
    char* Xb = lds + (TT & 1) * 20480;
    *(ushort8*)(Xb + sg_row * 128 + sg_slotx * 16) = xb;
    *(ushort8*)(xext + (row0 + sg_row) * KX + TT * 64 + sg_c * 8) = xb;
  };

  f32x4 acc[4] = {};

  // prologue: produce tile 0
  {
    const float* xp = x + (row0 + sg_row) * D_ + sg_c * 8;
    float4 a = *(const float4*)xp;
    float4 b = *(const float4*)(xp + 4);
    stageA(0);
    putX(0, a, b);
  }
  __syncthreads();

  for (int T = 0; T < HG_NKT; ++T) {
    float4 na, nb;
    const bool more = (T + 1 < HG_NKT);
    if (more) {
      const float* xp = x + (row0 + sg_row) * D_ + (T + 1) * 64 + sg_c * 8;
      na = *(const float4*)xp;
      nb = *(const float4*)(xp + 4);
      stageA(T + 1);
    }
    char* Xb = lds + (T & 1) * 20480;
    char* Ab = Xb + 4096;
    bf16x8 af[2], bfr[4][2];
    #pragma unroll
    for (int kk = 0; kk < 2; ++kk)
      af[kk] = *(const bf16x8*)(Xb + (wr * 16 + lr) * 128 + ((kk * 64 + lg * 16) ^ koff));
    #pragma unroll
    for (int nj = 0; nj < 4; ++nj) {
      const int R = wc * 64 + nj * 16 + lr;
      #pragma unroll
      for (int kk = 0; kk < 2; ++kk)
        bfr[nj][kk] = *(const bf16x8*)(Ab + R * 128 + ((kk * 64 + lg * 16) ^ koff));
    }
    #pragma unroll
    for (int nj = 0; nj < 4; ++nj)
      #pragma unroll
      for (int kk = 0; kk < 2; ++kk)
        acc[nj] = __builtin_amdgcn_mfma_f32_16x16x32_bf16(af[kk], bfr[nj][kk], acc[nj], 0, 0, 0);
    if (more) putX(T + 1, na, nb);
    __syncthreads();   // full drain: vmcnt (Ae tile) + lgkm (Xb writes)
  }

  // masked epilogue: xext[row][D_+col] = (eidx[row]==col>>4) ? bf16(2*h) : 0
  int er[4];
  #pragma unroll
  for (int rr = 0; rr < 4; ++rr)
    er[rr] = eidx[row0 + wr * 16 + lg * 4 + rr];
  #pragma unroll
  for (int nj = 0; nj < 4; ++nj) {
    const int col = wc * 64 + nj * 16 + lr;
    const int ecol = wc * 4 + nj;              // col>>4, wave-uniform per nj
    #pragma unroll
    for (int rr = 0; rr < 4; ++rr) {
      const size_t row = row0 + wr * 16 + lg * 4 + rr;
      ushort_t v = (er[rr] == ecol) ? f2bf(acc[nj][rr] * SCALING_F) : (ushort_t)0;
      xext[row * KX + D_ + col] = v;
    }
  }
}

// ---------------- GEMM: 256x256 tile, 8-phase schedule (m201 template) ------
// BM=BN=256, BK=64, 8 waves (2Mx4N), 512 thr, 128 KiB LDS double-buffer.
// T2 st-swizzle (slot^row&7 both sides), counted vmcnt(4)/K-tile, setprio.
//
// RACE-SAFE stage schedule (fixes round-3..5 latent race):
//   A-region of buffer T&1 is ds_read in EVERY phase of tile T -> A halves
//   may only be staged 1-ahead (into buffer (T+1)&1, never the read buffer).
//   B-region of buffer T&1 is ds_read ONLY at q=0 (cached in bq registers),
//   drained before q0's pre-MFMA lgkmcnt(0) -> B halves of tile T+2 are safe
//   to stage at q>=2 (after q0's post-MFMA barrier).
//   Per tile T: q0->A0(T+1), q1->A1(T+1), q2->B0(T+2), q3->B1(T+2).
//   vmcnt(4) at q3 leaves exactly B(T+2)'s 4 loads in flight.
#define NKT (KX / 64)        // 34 K-tiles
#define NSTG (NKT * 4)       // 136 half-tile stages

__global__ __launch_bounds__(512, 2) void gemm_kernel(
    const ushort_t* __restrict__ Ag,   // [M_][KX] bf16
    const ushort_t* __restrict__ Bg,   // [OUT_][KX] bf16
    const float* __restrict__ bias,
    float* __restrict__ C)
{
  __shared__ __attribute__((aligned(16))) char lds[131072];

  const int t = threadIdx.x;
  const int lane = t & 63, w = t >> 6;
  const int wm = w >> 2, wn = w & 3;          // 2x4 wave grid; wave tile 128x64
  const int lr = lane & 15, lg = lane >> 4;
  const int koff = (lr & 7) << 4;             // read-side swizzle XOR (bytes)

  // XCD-bijective blockIdx swizzle (512 % 8 == 0)
  const int swz = (blockIdx.x & 7) * 64 + (blockIdx.x >> 3);
  const int bm = swz >> 3, bn = swz & 7;

  // staging constants: thread t covers row (g*64 + t>>3), slot (t&7)
  const int sg_row = t >> 3;
  const int sg_slotx = (t & 7) ^ ((t >> 3) & 7);   // pre-swizzled source slot
  const size_t aRow0 = (size_t)bm * 256;
  const size_t bRow0 = (size_t)bn * 256;

  // stage half-tile s: tile TT=s>>2, j=s&3 (0,1 = A halves; 2,3 = B halves)
  auto stage = [&](int s) {
    if (s >= NSTG) return;
    const int TT = s >> 2, j = s & 3;
    const int isB = j >> 1, half = j & 1;
    const ushort_t* src = isB ? Bg : Ag;
    const size_t gr0 = (isB ? bRow0 : aRow0) + half * 128;
    char* dst = lds + (TT & 1) * 65536 + isB * 32768 + half * 16384;
    #pragma unroll
    for (int g = 0; g < 2; ++g) {
      const int r = g * 64 + sg_row;
      GLOAD16(src + (gr0 + r) * KX + TT * 64 + sg_slotx * 8,
              dst + g * 8192 + t * 16);
    }
  };

  f32x4 acc[8][4] = {};
  bf16x8 bq[4][2];

  // prologue: tile0 {A0,A1,B0,B1} + tile1 {B0,B1}; wait tile0 landed,
  // leaving tile1's B (4 loads) in flight.
  stage(0); stage(1); stage(2); stage(3);
  stage(6); stage(7);
  asm volatile("s_waitcnt vmcnt(4)" ::: "memory");
  __builtin_amdgcn_s_barrier();

  #pragma unroll 2
  for (int T = 0; T < NKT; ++T) {
    char* Ab = lds + (T & 1) * 65536;
    char* Bb = Ab + 32768;
    #pragma unroll
    for (int q = 0; q < 4; ++q) {
      // --- ds-load register subtile ---
      bf16x8 aq[2][2];
      if (q == 0) {
        #pragma unroll
        for (int nj = 0; nj < 4; ++nj) {
          const int R = wn * 64 + nj * 16 + lr;
          #pragma unroll
          for (int kk = 0; kk < 2; ++kk)
            bq[nj][kk] = *(const bf16x8*)(Bb + R * 128 + ((kk * 64 + lg * 16) ^ koff));
        }
      }
      #pragma unroll
      for (int i = 0; i < 2; ++i) {
        const int R = wm * 128 + (q * 2 + i) * 16 + lr;
        #pragma unroll
        for (int kk = 0; kk < 2; ++kk)
          aq[i][kk] = *(const bf16x8*)(Ab + R * 128 + ((kk * 64 + lg * 16) ^ koff));
      }
      // --- stage: q0/q1 -> A halves of T+1 (buffer (T+1)&1, never the read
      //     buffer); q2/q3 -> B halves of T+2 (B-region of buffer T&1, whose
      //     tile-T reads all drained before q0's post-MFMA barrier) ---
      stage(q < 2 ? 4 * (T + 1) + q : 4 * (T + 2) + q);
      if (q == 0) asm volatile("s_waitcnt lgkmcnt(8)" ::: "memory");
      __builtin_amdgcn_s_barrier();
      asm volatile("s_waitcnt lgkmcnt(0)" ::: "memory");
      // --- MFMA cluster: one C-quadrant (2 m-frags x 4 n-frags) x K=64 ---
      __builtin_amdgcn_s_setprio(1);
      #pragma unroll
      for (int i = 0; i < 2; ++i)
        #pragma unroll
        for (int nj = 0; nj < 4; ++nj)
          #pragma unroll
          for (int kk = 0; kk < 2; ++kk)
            acc[q * 2 + i][nj] = __builtin_amdgcn_mfma_f32_16x16x32_bf16(
                aq[i][kk], bq[nj][kk], acc[q * 2 + i][nj], 0, 0, 0);
      __builtin_amdgcn_s_setprio(0);
      if (q == 3) {
        // drain B(T+1)+A(T+1); leave B(T+2) (4 loads) in flight.
        if (T >= NKT - 2) asm volatile("s_waitcnt vmcnt(0)" ::: "memory");
        else              asm volatile("s_waitcnt vmcnt(4)" ::: "memory");
      }
      __builtin_amdgcn_s_barrier();
    }
  }

  // epilogue: C = acc + bias ; C/D layout col=lane&15, row=(lane>>4)*4+reg
  #pragma unroll
  for (int nj = 0; nj < 4; ++nj) {
    const int col = bn * 256 + wn * 64 + nj * 16 + lr;
    const float bv = bias[col];
    #pragma unroll
    for (int mi = 0; mi < 8; ++mi) {
      const int row0 = bm * 256 + wm * 128 + mi * 16 + lg * 4;
      #pragma unroll
      for (int rr = 0; rr < 4; ++rr)
        C[(size_t)(row0 + rr) * OUT_ + col] = acc[mi][nj][rr] + bv;
    }
  }
}

extern "C" void kernel_launch(void* const* d_in, const int* in_sizes, int n_in,
                              void* d_out, int out_size, void* d_ws, size_t ws_size,
                              hipStream_t stream) {
  const float* x  = (const float*)d_in[0];   // [4,4096,2048]
  const float* Wb = (const float*)d_in[1];   // [2048,2048]
  const float* bb = (const float*)d_in[2];   // [2048]
  const float* rW = (const float*)d_in[3];   // [8,2048]
  const float* A  = (const float*)d_in[4];   // [8,16,2048]
  const float* Bw = (const float*)d_in[5];   // [8,2048,16]
  float* out = (float*)d_out;                // [4,4096,2048] fp32

  ushort_t* xext = (ushort_t*)d_ws;                                   // M_ x KX bf16
  ushort_t* wext = (ushort_t*)((char*)d_ws + (size_t)M_ * KX * 2);    // OUT_ x KX bf16
  int* eidx = (int*)((char*)d_ws + (size_t)M_ * KX * 2 + (size_t)OUT_ * KX * 2);
  ushort_t* aext = (ushort_t*)((char*)eidx + M_ * sizeof(int));       // 128 x D_ bf16

  wprep_all_kernel<<<OUT_ + (E_ * R_ * D_) / (256 * 8), 256, 0, stream>>>(Wb, Bw, A, wext, aext);
  router_kernel<<<M_ / 16, 256, 0, stream>>>(x, rW, eidx);
  hgemm_kernel<<<M_ / 32, 256, 0, stream>>>(x, aext, eidx, xext);
  gemm_kernel<<<(M_ / 256) * (OUT_ / 256), 512, 0, stream>>>(xext, wext, bb, out);
}